// Round 5
// baseline (217.885 us; speedup 1.0000x reference)
//
#include <hip/hip_runtime.h>
#include <hip/hip_cooperative_groups.h>
#include <cstdint>
#include <cstddef>

namespace cg = cooperative_groups;

constexpr int O_C   = 16;     // objects per image
constexpr int CH    = 4;      // match chunks per batch
constexpr int CHP   = 2183;   // priors per chunk (4*2183 = 8732)
constexpr int P_MAX = 8732;
constexpr int NBLK  = 256;    // grid blocks (1 per CU, co-resident)
constexpr int NTHR  = 1024;
constexpr int RT    = 64;     // rows per ce tile
constexpr int TV4   = RT * 81 / 4;   // 1296 float4 per tile

__device__ __forceinline__ float waveSumF(float v) {
    #pragma unroll
    for (int off = 32; off; off >>= 1) v += __shfl_xor(v, off);
    return v;
}
__device__ __forceinline__ int waveSumI(int v) {
    #pragma unroll
    for (int off = 32; off; off >>= 1) v += __shfl_xor(v, off);
    return v;
}

__global__ __launch_bounds__(NTHR, 1) void mbloss_coop(
    const float* __restrict__ confs,          // [rows,81]
    const float* __restrict__ target_boxes,   // [B,O,4] xyxy
    const int*   __restrict__ target_labels,  // [B,O]
    const float* __restrict__ priors,         // [P,4] cxcywh
    const float* __restrict__ predict_locs,   // [rows,4]
    float* __restrict__ ov_g,                 // [rows]
    unsigned char* __restrict__ obj_g,        // [rows]
    unsigned long long* __restrict__ okey_part, // [B*CH*O]
    float* __restrict__ ce_g,                 // [rows] signed
    float* __restrict__ locsum_g,             // [NBLK]
    int*   __restrict__ n_pos_g,              // [B]
    float* __restrict__ ce_pos_g,             // [B]
    float* __restrict__ ce_hard_g,            // [B]
    float* __restrict__ out,
    int P, int B, int rows)
{
    cg::grid_group grid = cg::this_grid();
    const int bid  = blockIdx.x;
    const int tid  = threadIdx.x;
    const int lane = tid & 63;
    const int wid  = tid >> 6;   // 0..15

    __shared__ union {
        float x[2][RT * 81];                                  // ce double buffer (41472 B)
        struct { float v[P_MAX]; unsigned int hist[16][256]; } h; // hard (51312 B)
    } u;
    __shared__ float4 tbox[2][2][O_C];
    __shared__ int    ttlab[2][2][O_C], ttopr[2][2][O_C];
    __shared__ unsigned long long s_wb[O_C][16];
    __shared__ float s_mb[5][O_C];      // x0,y0,x1,y1,area for match phase
    __shared__ float s_f[16], s_f2[16];
    __shared__ int   s_i[16];
    __shared__ unsigned int s_sel;
    __shared__ int s_kr;

    // ===================== Phase M: matching =====================
    for (int chunk = bid; chunk < B * CH; chunk += NBLK) {
        const int b = chunk / CH, c = chunk % CH;
        if (tid < O_C) {
            const float* tb = target_boxes + ((size_t)b * O_C + tid) * 4;
            float x0 = tb[0], y0 = tb[1], x1 = tb[2], y1 = tb[3];
            s_mb[0][tid] = x0; s_mb[1][tid] = y0;
            s_mb[2][tid] = x1; s_mb[3][tid] = y1;
            s_mb[4][tid] = (x1 - x0) * (y1 - y0);
        }
        __syncthreads();

        float bi[O_C]; int bp[O_C];
        #pragma unroll
        for (int o = 0; o < O_C; ++o) { bi[o] = -1.0f; bp[o] = 0; }

        const int p0 = c * CHP, p1 = min(p0 + CHP, P);
        for (int p = p0 + tid; p < p1; p += NTHR) {
            float4 pr = reinterpret_cast<const float4*>(priors)[p];
            float px0 = pr.x - pr.z * 0.5f, py0 = pr.y - pr.w * 0.5f;
            float px1 = pr.x + pr.z * 0.5f, py1 = pr.y + pr.w * 0.5f;
            float parea = (px1 - px0) * (py1 - py0);
            float bv = -1.0f; int bo = 0;
            #pragma unroll
            for (int o = 0; o < O_C; ++o) {
                float ix0 = fmaxf(px0, s_mb[0][o]), iy0 = fmaxf(py0, s_mb[1][o]);
                float ix1 = fminf(px1, s_mb[2][o]), iy1 = fminf(py1, s_mb[3][o]);
                float iw = fmaxf(ix1 - ix0, 0.0f), ih = fmaxf(iy1 - iy0, 0.0f);
                float inter = iw * ih;
                float iou = inter / (s_mb[4][o] + parea - inter);
                if (iou > bv) { bv = iou; bo = o; }           // first-max (argmax over o)
                if (iou > bi[o]) { bi[o] = iou; bp[o] = p; }  // strict > -> smallest p
            }
            ov_g[(size_t)b * P + p]  = bv;
            obj_g[(size_t)b * P + p] = (unsigned char)bo;
        }

        #pragma unroll
        for (int o = 0; o < O_C; ++o) {
            unsigned long long k = (bi[o] >= 0.0f)
                ? (((unsigned long long)__float_as_uint(bi[o]) << 32) |
                   (unsigned long long)(0xFFFFFFFFu - (unsigned)bp[o]))
                : 0ull;
            #pragma unroll
            for (int off = 32; off; off >>= 1) {
                unsigned long long k2 = __shfl_xor(k, off);
                if (k2 > k) k = k2;
            }
            if (lane == 0) s_wb[o][wid] = k;
        }
        __syncthreads();
        if (tid < O_C) {
            unsigned long long k = s_wb[tid][0];
            #pragma unroll
            for (int w = 1; w < 16; ++w) if (s_wb[tid][w] > k) k = s_wb[tid][w];
            okey_part[(size_t)chunk * O_C + tid] = k;
        }
        __syncthreads();
    }
    grid.sync();

    // ===================== Phase C: fused CE (double-buffered) =====================
    const int ntile = rows / RT;           // 8732
    const int rl = tid >> 4, q = tid & 15; // 64 rows x 16 lanes
    const int sseg = q ? (5 * q + 1) : 0;  // 0,6,11,...,76
    float locacc = 0.0f;

    if (bid < ntile) {
        // prologue: stage tile bid into slot 0
        const float4* src0 = reinterpret_cast<const float4*>(confs + (size_t)bid * RT * 81);
        float4* dx0 = reinterpret_cast<float4*>(u.x[0]);
        dx0[tid] = src0[tid];
        if (tid < TV4 - NTHR) dx0[NTHR + tid] = src0[NTHR + tid];
        if (tid < 32) {
            const int seg = tid >> 4, o = tid & 15;
            const int row0 = bid * RT;
            const int b0 = row0 / P;
            const int rsp = min(row0 + RT, (b0 + 1) * P);
            const bool two = rsp < row0 + RT;
            const int bb = (seg && two) ? b0 + 1 : b0;
            const float* tb = target_boxes + ((size_t)bb * O_C + o) * 4;
            tbox[0][seg][o] = make_float4(tb[0], tb[1], tb[2], tb[3]);
            ttlab[0][seg][o] = target_labels[(size_t)bb * O_C + o];
            unsigned long long kk = 0ull;
            #pragma unroll
            for (int cc = 0; cc < CH; ++cc) {
                unsigned long long k2 = okey_part[((size_t)bb * CH + cc) * O_C + o];
                if (k2 > kk) kk = k2;
            }
            ttopr[0][seg][o] = (int)(0xFFFFFFFFu - (unsigned)(kk & 0xFFFFFFFFull));
        }
    }

    for (int t = bid, k = 0; t < ntile; t += NBLK, ++k) {
        const int slot = k & 1, ns = slot ^ 1;
        const int tn = t + NBLK;
        const bool have = tn < ntile;
        __syncthreads();   // slot staged; ns free (prev compute done)

        // issue next-tile loads into registers (latency hides under compute)
        float4 r0 = make_float4(0,0,0,0), r1 = make_float4(0,0,0,0);
        float4 trbox = make_float4(0,0,0,0); int trlab = 0, tropr = 0;
        int trseg = 0, tro = 0;
        if (have) {
            const float4* src = reinterpret_cast<const float4*>(confs + (size_t)tn * RT * 81);
            r0 = src[tid];
            if (tid < TV4 - NTHR) r1 = src[NTHR + tid];
            if (tid < 32) {
                trseg = tid >> 4; tro = tid & 15;
                const int row0n = tn * RT;
                const int b0n = row0n / P;
                const int rspn = min(row0n + RT, (b0n + 1) * P);
                const bool twon = rspn < row0n + RT;
                const int bb = (trseg && twon) ? b0n + 1 : b0n;
                const float* tb = target_boxes + ((size_t)bb * O_C + tro) * 4;
                trbox = make_float4(tb[0], tb[1], tb[2], tb[3]);
                trlab = target_labels[(size_t)bb * O_C + tro];
                unsigned long long kk = 0ull;
                #pragma unroll
                for (int cc = 0; cc < CH; ++cc) {
                    unsigned long long k2 = okey_part[((size_t)bb * CH + cc) * O_C + tro];
                    if (k2 > kk) kk = k2;
                }
                tropr = (int)(0xFFFFFFFFu - (unsigned)(kk & 0xFFFFFFFFull));
            }
        }

        // compute current tile from slot
        {
            const int row0 = t * RT;
            const int b0 = row0 / P;
            const int rsp = min(row0 + RT, (b0 + 1) * P);
            const int row = row0 + rl;
            const float* xr = &u.x[slot][rl * 81];

            float v[6];
            #pragma unroll
            for (int i = 0; i < 6; ++i)
                v[i] = (q == 0 || i < 5) ? xr[sseg + i] : -3.0e38f;
            // q==0 reads 6 (0..5); q>0 reads 5 valid, 6th masked
            if (q != 0) v[5] = -3.0e38f;

            float m = v[0];
            #pragma unroll
            for (int i = 1; i < 6; ++i) m = fmaxf(m, v[i]);
            m = fmaxf(m, __shfl_xor(m, 1));
            m = fmaxf(m, __shfl_xor(m, 2));
            m = fmaxf(m, __shfl_xor(m, 4));
            m = fmaxf(m, __shfl_xor(m, 8));

            float sum = 0.0f;
            #pragma unroll
            for (int i = 0; i < 6; ++i) sum += __expf(v[i] - m);
            sum += __shfl_xor(sum, 1);
            sum += __shfl_xor(sum, 2);
            sum += __shfl_xor(sum, 4);
            sum += __shfl_xor(sum, 8);

            if (q == 0) {
                const int seg = (row >= rsp) ? 1 : 0;
                const int bb = b0 + seg;
                const int p = row - bb * P;
                float ovv = ov_g[row];
                int obj = obj_g[row];
                #pragma unroll
                for (int o = 0; o < O_C; ++o)        // ascending -> last write wins
                    if (ttopr[slot][seg][o] == p) { obj = o; ovv = 1.0f; }
                const int l = (ovv < 0.5f) ? 0 : ttlab[slot][seg][obj];
                float cev = m + __logf(sum) - xr[l];
                ce_g[row] = l ? -cev : cev;          // sign carries pos/neg
                if (l) {
                    float4 pr = reinterpret_cast<const float4*>(priors)[p];
                    float4 tb = tbox[slot][seg][obj];
                    float cx = (tb.x + tb.z) * 0.5f, cy = (tb.y + tb.w) * 0.5f;
                    float w  = tb.z - tb.x,          h  = tb.w - tb.y;
                    float g0 = (cx - pr.x) / (pr.z * 0.1f);
                    float g1 = (cy - pr.y) / (pr.w * 0.1f);
                    float g2 = logf(w / pr.z) / 0.2f;
                    float g3 = logf(h / pr.w) / 0.2f;
                    float4 pl = reinterpret_cast<const float4*>(predict_locs)[row];
                    locacc += fabsf(pl.x - g0) + fabsf(pl.y - g1) +
                              fabsf(pl.z - g2) + fabsf(pl.w - g3);
                }
            }
        }

        // write staged next tile (write-late: vmcnt waits land here, after compute)
        if (have) {
            float4* dx = reinterpret_cast<float4*>(u.x[ns]);
            dx[tid] = r0;
            if (tid < TV4 - NTHR) dx[NTHR + tid] = r1;
            if (tid < 32) {
                tbox[ns][trseg][tro]  = trbox;
                ttlab[ns][trseg][tro] = trlab;
                ttopr[ns][trseg][tro] = tropr;
            }
        }
    }

    // block loc partial
    {
        float a = waveSumF(locacc);
        if (lane == 0) s_f[wid] = a;
        __syncthreads();
        if (tid == 0) {
            float sres = 0.0f;
            #pragma unroll
            for (int w = 0; w < 16; ++w) sres += s_f[w];
            locsum_g[bid] = sres;
        }
    }
    grid.sync();

    // ===================== Phase H: hard-negative mining =====================
    if (bid < B) {
        const int b = bid;
        const size_t base = (size_t)b * P;
        float possum = 0.0f, negsum = 0.0f;
        int cnt = 0;
        for (int p = tid; p < P; p += NTHR) {
            float c = ce_g[base + p];
            unsigned uu = __float_as_uint(c);
            float sv;
            if (uu >> 31) { possum += -c; ++cnt; sv = 0.0f; }
            else          { negsum += c;        sv = c;    }
            u.h.v[p] = sv;
        }
        possum = waveSumF(possum);
        negsum = waveSumF(negsum);
        cnt    = waveSumI(cnt);
        if (lane == 0) { s_f[wid] = possum; s_f2[wid] = negsum; s_i[wid] = cnt; }
        __syncthreads();
        float negsum_t = 0.0f, possum_t = 0.0f; int np = 0;
        #pragma unroll
        for (int w = 0; w < 16; ++w) { negsum_t += s_f2[w]; possum_t += s_f[w]; np += s_i[w]; }
        if (tid == 0) { ce_pos_g[b] = possum_t; n_pos_g[b] = np; }

        const int K = 3 * np;
        if (K > 0 && K < P) {
            unsigned int prefix = 0; int kr = K;
            for (int shift = 24; shift >= 0; shift -= 8) {
                for (int i = tid; i < 16 * 256; i += NTHR) (&u.h.hist[0][0])[i] = 0;
                __syncthreads();
                unsigned int maskHi = (shift == 24) ? 0u : (0xFFFFFFFFu << (shift + 8));
                for (int p = tid; p < P; p += NTHR) {
                    unsigned int uu = __float_as_uint(u.h.v[p]);
                    if ((uu & maskHi) == prefix)
                        atomicAdd(&u.h.hist[wid][(uu >> shift) & 255], 1u);
                }
                __syncthreads();
                if (wid == 0) {
                    unsigned h0 = 0, h1 = 0, h2 = 0, h3 = 0;
                    #pragma unroll 4
                    for (int w = 0; w < 16; ++w) {
                        h0 += u.h.hist[w][lane * 4 + 0];
                        h1 += u.h.hist[w][lane * 4 + 1];
                        h2 += u.h.hist[w][lane * 4 + 2];
                        h3 += u.h.hist[w][lane * 4 + 3];
                    }
                    unsigned own = h0 + h1 + h2 + h3;
                    unsigned tsum = own;                 // inclusive suffix over lanes
                    #pragma unroll
                    for (int off = 1; off < 64; off <<= 1) {
                        unsigned uu = __shfl_down(tsum, off);
                        if (lane + off >= 64) uu = 0;
                        tsum += uu;
                    }
                    unsigned Tnext = tsum - own;         // strictly-higher lanes
                    unsigned cum3 = Tnext;
                    unsigned cum2 = cum3 + h3;
                    unsigned cum1 = cum2 + h2;
                    unsigned cum0 = cum1 + h1;
                    unsigned kru = (unsigned)kr;
                    int selj = -1; unsigned cg2 = 0;
                    if      (cum3 < kru && kru <= cum3 + h3) { selj = 3; cg2 = cum3; }
                    else if (cum2 < kru && kru <= cum2 + h2) { selj = 2; cg2 = cum2; }
                    else if (cum1 < kru && kru <= cum1 + h1) { selj = 1; cg2 = cum1; }
                    else if (cum0 < kru && kru <= cum0 + h0) { selj = 0; cg2 = cum0; }
                    if (selj >= 0) {
                        s_sel = prefix | ((unsigned)(lane * 4 + selj) << shift);
                        s_kr  = kr - (int)cg2;
                    }
                }
                __syncthreads();
                prefix = s_sel; kr = s_kr;
                __syncthreads();
            }

            float sumgt = 0.0f;
            for (int p = tid; p < P; p += NTHR) {
                unsigned int uu = __float_as_uint(u.h.v[p]);
                if (uu > prefix) sumgt += u.h.v[p];
            }
            sumgt = waveSumF(sumgt);
            if (lane == 0) s_f[wid] = sumgt;
            __syncthreads();
            if (tid == 0) {
                float sg = 0.0f;
                #pragma unroll
                for (int w = 0; w < 16; ++w) sg += s_f[w];
                ce_hard_g[b] = sg + (float)kr * __uint_as_float(prefix);
            }
        } else {
            if (tid == 0) ce_hard_g[b] = (K <= 0) ? 0.0f : negsum_t;
        }
    }
    grid.sync();

    // ===================== Phase F: finalize =====================
    if (bid == 0) {
        float la = (tid < NBLK) ? locsum_g[tid] : 0.0f;
        la = waveSumF(la);
        if (lane == 0) s_f[wid] = la;
        if (tid < 64) {
            int np = 0; float cp = 0.0f, chd = 0.0f;
            for (int b2 = tid; b2 < B; b2 += 64) {
                np += n_pos_g[b2]; cp += ce_pos_g[b2]; chd += ce_hard_g[b2];
            }
            #pragma unroll
            for (int off = 32; off; off >>= 1) {
                np  += __shfl_xor(np, off);
                cp  += __shfl_xor(cp, off);
                chd += __shfl_xor(chd, off);
            }
            if (tid == 0) { s_f2[0] = cp; s_f2[1] = chd; s_i[0] = np; }
        }
        __syncthreads();
        if (tid == 0) {
            float latot = 0.0f;
            #pragma unroll
            for (int w = 0; w < 16; ++w) latot += s_f[w];
            float npt = (float)s_i[0];
            out[0] = (s_f2[1] + s_f2[0]) / npt + latot / (npt * 4.0f);
        }
    }
}

extern "C" void kernel_launch(void* const* d_in, const int* in_sizes, int n_in,
                              void* d_out, int out_size, void* d_ws, size_t ws_size,
                              hipStream_t stream) {
    const float* predict_locs  = (const float*)d_in[0];
    const float* predict_confs = (const float*)d_in[1];
    const float* target_boxes  = (const float*)d_in[2];
    const int*   target_labels = (const int*)d_in[3];
    const float* priors        = (const float*)d_in[4];

    int P = in_sizes[4] / 4;              // 8732
    int B = in_sizes[0] / (P * 4);        // 64
    int rows = B * P;                     // 558848

    char* ws = (char*)d_ws;
    unsigned long long* okey_part = (unsigned long long*)ws;
    ws += (size_t)B * CH * O_C * sizeof(unsigned long long);
    float* ce      = (float*)ws; ws += (size_t)rows * sizeof(float);
    float* ov      = (float*)ws; ws += (size_t)rows * sizeof(float);
    float* locsum  = (float*)ws; ws += (size_t)NBLK * sizeof(float);
    int*   n_pos   = (int*)ws;   ws += (size_t)B * sizeof(int);
    float* ce_pos  = (float*)ws; ws += (size_t)B * sizeof(float);
    float* ce_hard = (float*)ws; ws += (size_t)B * sizeof(float);
    unsigned char* obj = (unsigned char*)ws; ws += (size_t)rows;
    float* outp = (float*)d_out;

    void* args[] = {
        (void*)&predict_confs, (void*)&target_boxes, (void*)&target_labels,
        (void*)&priors, (void*)&predict_locs,
        (void*)&ov, (void*)&obj, (void*)&okey_part, (void*)&ce, (void*)&locsum,
        (void*)&n_pos, (void*)&ce_pos, (void*)&ce_hard, (void*)&outp,
        (void*)&P, (void*)&B, (void*)&rows
    };
    hipLaunchCooperativeKernel((void*)mbloss_coop, dim3(NBLK), dim3(NTHR),
                               args, 0, stream);
}

// Round 6
// 78.322 us; speedup vs baseline: 2.7819x; 2.7819x over previous
//
#include <hip/hip_runtime.h>
#include <cstdint>
#include <cstddef>

constexpr int O_C   = 16;     // objects per image
constexpr int P_MAX = 8732;   // priors
constexpr int CH    = 4;      // match chunks per batch
constexpr int CHP   = 2183;   // priors per chunk (4*2183 = 8732)

struct f4u { float x, y, z, w; };   // 4-byte-aligned quad (rows are 324 B)

__device__ __forceinline__ float waveSumF(float v) {
    #pragma unroll
    for (int off = 32; off; off >>= 1) v += __shfl_xor(v, off);
    return v;
}
__device__ __forceinline__ int waveSumI(int v) {
    #pragma unroll
    for (int off = 32; off; off >>= 1) v += __shfl_xor(v, off);
    return v;
}

// ---------------------------------------------------------------------------
// A1: per-prior IoU argmax over objects + per-(chunk,object) best-prior key.
// grid = B*CH blocks, 256 thr. No atomics: each block owns okey_part slice.
// ---------------------------------------------------------------------------
__global__ __launch_bounds__(256) void matchA1(
    const float* __restrict__ target_boxes,   // [B,O,4] xyxy
    const float* __restrict__ priors,         // [P,4] cxcywh
    float* __restrict__ ov_out,               // [B,P]
    unsigned char* __restrict__ obj_out,      // [B,P]
    unsigned long long* __restrict__ okey_part, // [B*CH*O]
    int P)
{
    const int b    = blockIdx.x / CH;
    const int c    = blockIdx.x % CH;
    const int tid  = threadIdx.x;
    const int lane = tid & 63;
    const int wid  = tid >> 6;

    __shared__ float bx0[O_C], by0[O_C], bx1[O_C], by1[O_C], barea[O_C];
    __shared__ unsigned long long s_wb[O_C * 4];

    if (tid < O_C) {
        const float* tb = target_boxes + ((size_t)b * O_C + tid) * 4;
        float x0 = tb[0], y0 = tb[1], x1 = tb[2], y1 = tb[3];
        bx0[tid] = x0; by0[tid] = y0; bx1[tid] = x1; by1[tid] = y1;
        barea[tid] = (x1 - x0) * (y1 - y0);
    }
    __syncthreads();

    float bi[O_C]; int bp[O_C];
    #pragma unroll
    for (int o = 0; o < O_C; ++o) { bi[o] = -1.0f; bp[o] = 0; }

    const int p0 = c * CHP, p1 = min(p0 + CHP, P);
    for (int p = p0 + tid; p < p1; p += 256) {
        float4 pr = reinterpret_cast<const float4*>(priors)[p];
        float px0 = pr.x - pr.z * 0.5f, py0 = pr.y - pr.w * 0.5f;
        float px1 = pr.x + pr.z * 0.5f, py1 = pr.y + pr.w * 0.5f;
        float parea = (px1 - px0) * (py1 - py0);
        float bv = -1.0f; int bo = 0;
        #pragma unroll
        for (int o = 0; o < O_C; ++o) {
            float ix0 = fmaxf(px0, bx0[o]), iy0 = fmaxf(py0, by0[o]);
            float ix1 = fminf(px1, bx1[o]), iy1 = fminf(py1, by1[o]);
            float iw = fmaxf(ix1 - ix0, 0.0f), ih = fmaxf(iy1 - iy0, 0.0f);
            float inter = iw * ih;
            float iou = inter / (barea[o] + parea - inter);
            if (iou > bv) { bv = iou; bo = o; }          // first-max (argmax over o)
            if (iou > bi[o]) { bi[o] = iou; bp[o] = p; } // strict > -> smallest p
        }
        ov_out[(size_t)b * P + p]  = bv;
        obj_out[(size_t)b * P + p] = (unsigned char)bo;
    }

    // reduce per-object candidates: key = iou_bits<<32 | ~p (ties -> smaller p)
    #pragma unroll
    for (int o = 0; o < O_C; ++o) {
        unsigned long long k = (bi[o] >= 0.0f)
            ? (((unsigned long long)__float_as_uint(bi[o]) << 32) |
               (unsigned long long)(0xFFFFFFFFu - (unsigned)bp[o]))
            : 0ull;
        #pragma unroll
        for (int off = 32; off; off >>= 1) {
            unsigned long long k2 = __shfl_xor(k, off);
            if (k2 > k) k = k2;
        }
        if (lane == 0) s_wb[o * 4 + wid] = k;
    }
    __syncthreads();
    if (tid < O_C) {
        unsigned long long k = s_wb[tid * 4];
        #pragma unroll
        for (int w = 1; w < 4; ++w) if (s_wb[tid * 4 + w] > k) k = s_wb[tid * 4 + w];
        okey_part[(size_t)blockIdx.x * O_C + tid] = k;   // [b][c][o]
    }
}

// ---------------------------------------------------------------------------
// B-stream: thread-per-row fused CE. Online (flash-style) log-sum-exp over
// the 81 logits via 20 unaligned float4 loads + 1 scalar; no LDS staging,
// no barriers, no cross-lane ops. Label machinery + loc partial fused.
// Writes SIGNED ce (negative <=> positive prior).
// ---------------------------------------------------------------------------
__global__ __launch_bounds__(256) void ce_stream(
    const float* __restrict__ confs,            // [rows,81]
    const float* __restrict__ ov_in,            // [rows]
    const unsigned char* __restrict__ obj_in,   // [rows]
    const unsigned long long* __restrict__ okey_part, // [B*CH*O]
    const float* __restrict__ target_boxes,     // [B,O,4]
    const int*   __restrict__ target_labels,    // [B,O]
    const float* __restrict__ priors,           // [P,4]
    const float* __restrict__ predict_locs,     // [rows,4]
    float* __restrict__ ce_out,                 // [rows] signed
    float* __restrict__ loc_part,               // [nblocks]
    int P, int rows)
{
    const int tid  = threadIdx.x;
    const int lane = tid & 63;
    const int wid  = tid >> 6;
    const int row0 = blockIdx.x * 256;
    const int row  = row0 + tid;

    __shared__ float4 tbox[2][O_C];
    __shared__ int    tlab[2][O_C], topr[2][O_C];
    __shared__ float  s_facc[4];

    const int b0     = row0 / P;
    const int rsplit = min(row0 + 256, (b0 + 1) * P);
    const int b1     = (rsplit < row0 + 256) ? b0 + 1 : b0;

    if (tid < 2 * O_C) {
        const int seg = tid >> 4, o = tid & 15;
        const int bb  = seg ? b1 : b0;
        const float* tb = target_boxes + ((size_t)bb * O_C + o) * 4;
        tbox[seg][o] = make_float4(tb[0], tb[1], tb[2], tb[3]);
        tlab[seg][o] = target_labels[(size_t)bb * O_C + o];
        unsigned long long kk = 0ull;
        #pragma unroll
        for (int cc = 0; cc < CH; ++cc) {
            unsigned long long k2 = okey_part[((size_t)bb * CH + cc) * O_C + o];
            if (k2 > kk) kk = k2;
        }
        topr[seg][o] = (int)(0xFFFFFFFFu - (unsigned)(kk & 0xFFFFFFFFull));
    }
    __syncthreads();

    // ---- streaming log-sum-exp over 81 logits ----
    const float* rbase = confs + (size_t)row * 81;
    const f4u* rp = reinterpret_cast<const f4u*>(rbase);
    float m = -3.0e38f, s = 0.0f;
    #pragma unroll
    for (int j = 0; j < 20; ++j) {
        f4u a = rp[j];
        float m4 = fmaxf(fmaxf(a.x, a.y), fmaxf(a.z, a.w));
        float mn = fmaxf(m, m4);
        s = s * __expf(m - mn)
          + __expf(a.x - mn) + __expf(a.y - mn)
          + __expf(a.z - mn) + __expf(a.w - mn);
        m = mn;
    }
    {
        float last = rbase[80];
        float mn = fmaxf(m, last);
        s = s * __expf(m - mn) + __expf(last - mn);
        m = mn;
    }

    // ---- label + signed ce + loc partial ----
    const int seg = (row >= rsplit) ? 1 : 0;
    const int bb  = seg ? b1 : b0;
    const int p   = row - bb * P;
    float ovv = ov_in[row];
    int   obj = obj_in[row];
    #pragma unroll
    for (int o = 0; o < O_C; ++o)              // ascending -> last write wins
        if (topr[seg][o] == p) { obj = o; ovv = 1.0f; }
    const int l = (ovv < 0.5f) ? 0 : tlab[seg][obj];

    float xl  = rbase[l];                      // L1/L2-hot after the stream
    float cev = m + __logf(s) - xl;
    ce_out[row] = l ? -cev : cev;              // sign bit carries pos/neg

    float locacc = 0.0f;
    if (l) {
        float4 pr = reinterpret_cast<const float4*>(priors)[p];
        float4 tb = tbox[seg][obj];
        float cx = (tb.x + tb.z) * 0.5f, cy = (tb.y + tb.w) * 0.5f;
        float w  = tb.z - tb.x,          h  = tb.w - tb.y;
        float g0 = (cx - pr.x) / (pr.z * 0.1f);
        float g1 = (cy - pr.y) / (pr.w * 0.1f);
        float g2 = logf(w / pr.z) / 0.2f;
        float g3 = logf(h / pr.w) / 0.2f;
        float4 pl = reinterpret_cast<const float4*>(predict_locs)[row];
        locacc = fabsf(pl.x - g0) + fabsf(pl.y - g1) +
                 fabsf(pl.z - g2) + fabsf(pl.w - g3);
    }
    float a = waveSumF(locacc);
    if (lane == 0) s_facc[wid] = a;
    __syncthreads();
    if (tid == 0)
        loc_part[blockIdx.x] = s_facc[0] + s_facc[1] + s_facc[2] + s_facc[3];
}

// ---------------------------------------------------------------------------
// C: per-batch hard-negative mining from signed ce. Derives n_pos via
// signbit count; exact top-K sum via radix select (privatized histograms +
// wave-parallel suffix-scan digit select).
// ---------------------------------------------------------------------------
__global__ __launch_bounds__(1024) void hard_kernel(
    const float* __restrict__ ce,      // [B,P] signed
    int*   __restrict__ n_pos,         // [B]
    float* __restrict__ ce_pos,        // [B]
    float* __restrict__ ce_hard,       // [B]
    int P)
{
    const int b    = blockIdx.x;
    const int tid  = threadIdx.x;
    const int lane = tid & 63;
    const int wid  = tid >> 6;

    __shared__ float s_v[P_MAX];
    __shared__ unsigned int hist[16][256];
    __shared__ unsigned int s_sel;
    __shared__ int s_kr;
    __shared__ float s_f[16], s_f2[16];
    __shared__ int s_i[16];

    const size_t base = (size_t)b * P;
    float possum = 0.0f, negsum = 0.0f;
    int cnt = 0;
    for (int p = tid; p < P; p += 1024) {
        float c = ce[base + p];
        unsigned u = __float_as_uint(c);
        float sv;
        if (u >> 31) { possum += -c; ++cnt; sv = 0.0f; }
        else         { negsum += c;         sv = c;    }
        s_v[p] = sv;
    }
    possum = waveSumF(possum);
    negsum = waveSumF(negsum);
    cnt    = waveSumI(cnt);
    if (lane == 0) { s_f[wid] = possum; s_f2[wid] = negsum; s_i[wid] = cnt; }
    __syncthreads();
    float negsum_t = 0.0f, possum_t = 0.0f; int np = 0;
    #pragma unroll
    for (int w = 0; w < 16; ++w) { negsum_t += s_f2[w]; possum_t += s_f[w]; np += s_i[w]; }
    if (tid == 0) { ce_pos[b] = possum_t; n_pos[b] = np; }

    const int K = 3 * np;
    if (K <= 0) { if (tid == 0) ce_hard[b] = 0.0f; return; }
    if (K >= P) { if (tid == 0) ce_hard[b] = negsum_t; return; }

    unsigned int prefix = 0; int kr = K;
    for (int shift = 24; shift >= 0; shift -= 8) {
        for (int i = tid; i < 16 * 256; i += 1024) (&hist[0][0])[i] = 0;
        __syncthreads();
        unsigned int maskHi = (shift == 24) ? 0u : (0xFFFFFFFFu << (shift + 8));
        for (int p = tid; p < P; p += 1024) {
            unsigned int u = __float_as_uint(s_v[p]);
            if ((u & maskHi) == prefix) atomicAdd(&hist[wid][(u >> shift) & 255], 1u);
        }
        __syncthreads();
        if (wid == 0) {
            unsigned h0 = 0, h1 = 0, h2 = 0, h3 = 0;
            #pragma unroll 4
            for (int w = 0; w < 16; ++w) {
                h0 += hist[w][lane * 4 + 0];
                h1 += hist[w][lane * 4 + 1];
                h2 += hist[w][lane * 4 + 2];
                h3 += hist[w][lane * 4 + 3];
            }
            unsigned own = h0 + h1 + h2 + h3;
            unsigned t = own;                    // inclusive suffix over lanes
            #pragma unroll
            for (int off = 1; off < 64; off <<= 1) {
                unsigned u = __shfl_down(t, off);
                if (lane + off >= 64) u = 0;
                t += u;
            }
            unsigned Tnext = t - own;            // strictly-higher lanes
            unsigned cum3 = Tnext;
            unsigned cum2 = cum3 + h3;
            unsigned cum1 = cum2 + h2;
            unsigned cum0 = cum1 + h1;
            unsigned kru = (unsigned)kr;
            int selj = -1; unsigned cg = 0;
            if      (cum3 < kru && kru <= cum3 + h3) { selj = 3; cg = cum3; }
            else if (cum2 < kru && kru <= cum2 + h2) { selj = 2; cg = cum2; }
            else if (cum1 < kru && kru <= cum1 + h1) { selj = 1; cg = cum1; }
            else if (cum0 < kru && kru <= cum0 + h0) { selj = 0; cg = cum0; }
            if (selj >= 0) {
                s_sel = prefix | ((unsigned)(lane * 4 + selj) << shift);
                s_kr  = kr - (int)cg;
            }
        }
        __syncthreads();
        prefix = s_sel; kr = s_kr;
        __syncthreads();
    }

    float sumgt = 0.0f;
    for (int p = tid; p < P; p += 1024) {
        unsigned int u = __float_as_uint(s_v[p]);
        if (u > prefix) sumgt += s_v[p];
    }
    sumgt = waveSumF(sumgt);
    if (lane == 0) s_f[wid] = sumgt;
    __syncthreads();
    if (tid == 0) {
        float sg = 0.0f;
        #pragma unroll
        for (int w = 0; w < 16; ++w) sg += s_f[w];
        ce_hard[b] = sg + (float)kr * __uint_as_float(prefix);
    }
}

// ---------------------------------------------------------------------------
// D: finalize scalar loss. 256 thr, deterministic fixed-order sums.
// ---------------------------------------------------------------------------
__global__ __launch_bounds__(256) void finalize_kernel(
    const int*   __restrict__ n_pos,    // [B]
    const float* __restrict__ ce_pos,   // [B]
    const float* __restrict__ ce_hard,  // [B]
    const float* __restrict__ loc_part, // [nblk]
    float* __restrict__ out, int B, int nblk)
{
    __shared__ float s_f[4];
    __shared__ float s_res[3];
    const int tid  = threadIdx.x;
    const int lane = tid & 63;
    const int wid  = tid >> 6;

    float la = 0.0f;
    for (int i = tid; i < nblk; i += 256) la += loc_part[i];
    la = waveSumF(la);
    if (lane == 0) s_f[wid] = la;

    if (tid < 64) {
        int np = 0; float cp = 0.0f, ch = 0.0f;
        for (int b = lane; b < B; b += 64) {
            np += n_pos[b]; cp += ce_pos[b]; ch += ce_hard[b];
        }
        #pragma unroll
        for (int off = 32; off; off >>= 1) {
            np += __shfl_xor(np, off);
            cp += __shfl_xor(cp, off);
            ch += __shfl_xor(ch, off);
        }
        if (lane == 0) {
            s_res[0] = (float)np; s_res[1] = cp; s_res[2] = ch;
        }
    }
    __syncthreads();
    if (tid == 0) {
        float latot = s_f[0] + s_f[1] + s_f[2] + s_f[3];
        float npt = s_res[0];
        out[0] = (s_res[2] + s_res[1]) / npt + latot / (npt * 4.0f);
    }
}

extern "C" void kernel_launch(void* const* d_in, const int* in_sizes, int n_in,
                              void* d_out, int out_size, void* d_ws, size_t ws_size,
                              hipStream_t stream) {
    const float* predict_locs  = (const float*)d_in[0];
    const float* predict_confs = (const float*)d_in[1];
    const float* target_boxes  = (const float*)d_in[2];
    const int*   target_labels = (const int*)d_in[3];
    const float* priors        = (const float*)d_in[4];

    const int P = in_sizes[4] / 4;             // 8732
    const int B = in_sizes[0] / (P * 4);       // 64
    const int rows = B * P;                    // 558848
    const int nblk = rows / 256;               // 2183 (rows % 256 == 0)

    char* ws = (char*)d_ws;
    unsigned long long* okey_part = (unsigned long long*)ws;
    ws += (size_t)B * CH * O_C * sizeof(unsigned long long);
    float* ce      = (float*)ws; ws += (size_t)rows * sizeof(float);
    float* ov      = (float*)ws; ws += (size_t)rows * sizeof(float);
    float* loc_p   = (float*)ws; ws += (size_t)nblk * sizeof(float);
    int*   n_pos   = (int*)ws;   ws += (size_t)B * sizeof(int);
    float* ce_pos  = (float*)ws; ws += (size_t)B * sizeof(float);
    float* ce_hard = (float*)ws; ws += (size_t)B * sizeof(float);
    unsigned char* obj = (unsigned char*)ws; ws += (size_t)rows;

    matchA1<<<B * CH, 256, 0, stream>>>(target_boxes, priors, ov, obj, okey_part, P);
    ce_stream<<<nblk, 256, 0, stream>>>(predict_confs, ov, obj, okey_part,
                                        target_boxes, target_labels, priors,
                                        predict_locs, ce, loc_p, P, rows);
    hard_kernel<<<B, 1024, 0, stream>>>(ce, n_pos, ce_pos, ce_hard, P);
    finalize_kernel<<<1, 256, 0, stream>>>(n_pos, ce_pos, ce_hard, loc_p,
                                           (float*)d_out, B, rows / 256);
}